// Round 2
// baseline (379.288 us; speedup 1.0000x reference)
//
#include <hip/hip_runtime.h>
#include <hip/hip_bf16.h>
#include <math.h>

// Problem constants
#define BPART   524288
#define MT      128            // particles per block
#define NBLK    (BPART / MT)   // 4096
#define W7_OFF  98304          // 6 * 16384 bf16
#define WB_N    102400         // + 32*128 (padded W7t), bf16 count
#define BIAS_N  800            // 6*128 + 32 floats
#define PREP_N  (WB_N + BIAS_N)

typedef __bf16 bf16x8 __attribute__((ext_vector_type(8)));
typedef float  f32x16 __attribute__((ext_vector_type(16)));

__device__ __forceinline__ unsigned short f2bf(float f) {
  union { float f; unsigned u; } v; v.f = f;
  unsigned r = v.u + 0x7fffu + ((v.u >> 16) & 1u);   // RNE
  return (unsigned short)(r >> 16);
}
// XOR-swizzled LDS index (16B chunk swizzle; row stride 128 bf16 = 256B)
__device__ __forceinline__ int swz(int row, int col) {
  return (row << 7) | ((((col >> 3) ^ (row & 7)) << 3) | (col & 7));
}
// tanh-form GELU (max abs err ~1.5e-4 << bf16 rounding budget)
__device__ __forceinline__ float gelu_t(float z) {
  float z2 = z * z;
  float y  = z * (0.7978845608028654f + 0.035677408136300125f * z2);
  float e  = __expf(2.0f * y);
  float t  = 1.0f - 2.0f * __builtin_amdgcn_rcpf(e + 1.0f);
  return 0.5f * z * (1.0f + t);
}

// ---- prep: cast+transpose fp32 weights into d_ws (bf16 Wt) + fp32 biases ----
__global__ void prep_weights(
    const float* __restrict__ W1, const float* __restrict__ W2,
    const float* __restrict__ W3, const float* __restrict__ W4,
    const float* __restrict__ W5, const float* __restrict__ W6,
    const float* __restrict__ W7,
    const float* __restrict__ b1, const float* __restrict__ b2,
    const float* __restrict__ b3, const float* __restrict__ b4,
    const float* __restrict__ b5, const float* __restrict__ b6,
    const float* __restrict__ b7,
    unsigned short* __restrict__ wsb, float* __restrict__ wsf)
{
  int idx = blockIdx.x * 256 + threadIdx.x;
  if (idx < WB_N) {
    unsigned short v = 0;
    if (idx < W7_OFF) {                     // W1..W6 transposed, 128x128 each
      int l = idx >> 14;
      int r = idx & 16383;
      int n = r >> 7, k = r & 127;
      const float* W = (l==0)?W1:(l==1)?W2:(l==2)?W3:(l==3)?W4:(l==4)?W5:W6;
      float x = (l == 0) ? ((k < 89) ? W[k*128 + n] : 0.0f)   // K-pad 89->128
                         : W[k*128 + n];
      v = f2bf(x);
    } else {                                // W7 transposed, padded to 32x128
      int r = idx - W7_OFF;
      int n = r >> 7, k = r & 127;
      v = (n < 9) ? f2bf(W7[k*9 + n]) : (unsigned short)0;
    }
    wsb[idx] = v;
  } else if (idx < PREP_N) {                // biases, kept fp32
    int r = idx - WB_N;
    float x;
    if (r < 768) {
      int l = r >> 7, n = r & 127;
      const float* bb = (l==0)?b1:(l==1)?b2:(l==2)?b3:(l==3)?b4:(l==4)?b5:b6;
      x = bb[n];
    } else {
      int n = r - 768;
      x = (n < 9) ? b7[n] : 0.0f;
    }
    wsf[r] = x;
  }
}

// ---- main fused kernel: features + 7-layer MLP + symmetrize ----
__global__ __launch_bounds__(256, 2) void stress_mlp(
    const float* __restrict__ F, const float* __restrict__ Cmat,
    const int* __restrict__ traj, const float* __restrict__ latent,
    const unsigned short* __restrict__ wst, const float* __restrict__ wsf,
    float* __restrict__ out)
{
  __shared__ __align__(16) unsigned short act_s[128 * 128];  // 32 KB
  __shared__ __align__(16) unsigned short wt_s[128 * 128];   // 32 KB

  const int tid  = threadIdx.x;
  const int lane = tid & 63;
  const int wid  = tid >> 6;
  const int lm   = lane & 31;
  const int lk   = lane >> 5;              // k-half: lanes 0-31 -> k0..7, 32-63 -> k8..15
  const int m0   = (wid >> 1) << 6;        // wave row origin (0 or 64)
  const int n0   = (wid & 1) << 6;         // wave col origin (0 or 64)
  const int pbase = (int)blockIdx.x << 7;

  // ---------- phase 0: build input activations (89 feats, zero-pad to 128) ----------
  if (tid < 128) {
    const int row = tid;
    const int p   = pbase + row;
    float f[9];
    #pragma unroll
    for (int i = 0; i < 9; ++i) f[i] = F[p * 9 + i];
    float fft[9];
    #pragma unroll
    for (int i = 0; i < 3; ++i)
      #pragma unroll
      for (int k = 0; k < 3; ++k)
        fft[i*3+k] = f[i*3]*f[k*3] + f[i*3+1]*f[k*3+1] + f[i*3+2]*f[k*3+2];
    float det = f[0]*(f[4]*f[8]-f[5]*f[7]) - f[1]*(f[3]*f[8]-f[5]*f[6])
              + f[2]*(f[3]*f[7]-f[4]*f[6]);
    float J  = fmaxf(det, 1e-6f);
    float J1 = fmaxf(f[0], 1e-6f);
    // singular values = sqrt(eig(F F^T)); analytic symmetric 3x3 eigensolve (fp64)
    double a00=fft[0], a01=fft[1], a02=fft[2], a11=fft[4], a12=fft[5], a22=fft[8];
    double q  = (a00+a11+a22) * (1.0/3.0);
    double d0 = a00-q, d1 = a11-q, d2 = a22-q;
    double p2 = d0*d0 + d1*d1 + d2*d2 + 2.0*(a01*a01 + a02*a02 + a12*a12);
    double e0, e1, e2;
    if (p2 < 1e-26) { e0 = e1 = e2 = q; }
    else {
      double pp = sqrt(p2 * (1.0/6.0));
      double inv = 1.0 / pp;
      double b00=d0*inv, b11=d1*inv, b22=d2*inv, b01=a01*inv, b02=a02*inv, b12=a12*inv;
      double detb = b00*(b11*b22-b12*b12) - b01*(b01*b22-b12*b02) + b02*(b01*b12-b11*b02);
      double rr = 0.5 * detb;
      rr = rr > 1.0 ? 1.0 : (rr < -1.0 ? -1.0 : rr);
      double phi = acos(rr) * (1.0/3.0);
      e0 = q + 2.0*pp*cos(phi);
      e2 = q + 2.0*pp*cos(phi + 2.0943951023931953);  // +2pi/3
      e1 = 3.0*q - e0 - e2;
    }
    float s0 = sqrtf(fmaxf((float)e0, 0.f));
    float s1 = sqrtf(fmaxf((float)e1, 0.f));
    float s2 = sqrtf(fmaxf((float)e2, 0.f));
    #pragma unroll
    for (int i = 0; i < 9; ++i) act_s[swz(row, i)] = f2bf(fft[i]);
    act_s[swz(row,  9)] = f2bf(logf(J));
    act_s[swz(row, 10)] = f2bf(s0);
    act_s[swz(row, 11)] = f2bf(s1);
    act_s[swz(row, 12)] = f2bf(s2);
    act_s[swz(row, 13)] = f2bf(J);
    act_s[swz(row, 14)] = f2bf(logf(J1));
    act_s[swz(row, 15)] = f2bf(J1);
    #pragma unroll
    for (int i = 0; i < 9; ++i) act_s[swz(row, 16 + i)] = f2bf(Cmat[p*9 + i]);
  } else {
    const int row = tid - 128;
    const int t = traj[0];
    const float* lat = latent + t * 64;
    for (int j = 0; j < 64; ++j) act_s[swz(row, 25 + j)] = f2bf(lat[j]);
    for (int j = 89; j < 128; ++j) act_s[swz(row, j)] = 0;
  }

  const int rA0 = m0 + lm,     rA1 = m0 + 32 + lm;
  const int rB0 = n0 + lm,     rB1 = n0 + 32 + lm;

  f32x16 acc[2][2];

  // ---------- layers 1..6 (128x128, gelu) ----------
  for (int l = 0; l < 6; ++l) {
    const unsigned short* src = wst + (l << 14);
    #pragma unroll
    for (int i = 0; i < 8; ++i) {            // stage W_t -> LDS (swizzled)
      int s = (i << 8) + tid;
      int n = s >> 4, cp = s & 15;
      int4 v = ((const int4*)src)[s];
      *reinterpret_cast<int4*>(&wt_s[(n << 7) + ((cp ^ (n & 7)) << 3)]) = v;
    }
    __syncthreads();                         // weights ready; prev act writes visible

    #pragma unroll
    for (int tm = 0; tm < 2; ++tm)
      #pragma unroll
      for (int tn = 0; tn < 2; ++tn)
        #pragma unroll
        for (int r = 0; r < 16; ++r) acc[tm][tn][r] = 0.0f;

    #pragma unroll
    for (int kk = 0; kk < 8; ++kk) {
      const int kc = (kk << 1) + lk;
      bf16x8 a0 = *(const bf16x8*)&act_s[(rA0 << 7) + ((kc ^ (rA0 & 7)) << 3)];
      bf16x8 a1 = *(const bf16x8*)&act_s[(rA1 << 7) + ((kc ^ (rA1 & 7)) << 3)];
      bf16x8 b0 = *(const bf16x8*)&wt_s[(rB0 << 7) + ((kc ^ (rB0 & 7)) << 3)];
      bf16x8 b1 = *(const bf16x8*)&wt_s[(rB1 << 7) + ((kc ^ (rB1 & 7)) << 3)];
      acc[0][0] = __builtin_amdgcn_mfma_f32_32x32x16_bf16(a0, b0, acc[0][0], 0, 0, 0);
      acc[0][1] = __builtin_amdgcn_mfma_f32_32x32x16_bf16(a0, b1, acc[0][1], 0, 0, 0);
      acc[1][0] = __builtin_amdgcn_mfma_f32_32x32x16_bf16(a1, b0, acc[1][0], 0, 0, 0);
      acc[1][1] = __builtin_amdgcn_mfma_f32_32x32x16_bf16(a1, b1, acc[1][1], 0, 0, 0);
    }
    __syncthreads();                         // all act/wt reads done before overwrite

    #pragma unroll
    for (int tn = 0; tn < 2; ++tn) {
      const int col = n0 + (tn << 5) + lm;
      const float bcol = wsf[(l << 7) + col];
      #pragma unroll
      for (int tm = 0; tm < 2; ++tm) {
        const int rbase = m0 + (tm << 5) + (lk << 2);
        #pragma unroll
        for (int r = 0; r < 16; ++r) {
          const int row = rbase + (r & 3) + ((r >> 2) << 3);  // verified C/D layout
          float z = acc[tm][tn][r] + bcol;
          act_s[swz(row, col)] = f2bf(gelu_t(z));
        }
      }
    }
  }

  // ---------- layer 7 (128 -> 9, no activation) + symmetrize, fp32 path ----------
  {
    const unsigned short* src = wst + W7_OFF;
    #pragma unroll
    for (int i = 0; i < 2; ++i) {
      int s = (i << 8) + tid;
      int n = s >> 4, cp = s & 15;
      int4 v = ((const int4*)src)[s];
      *reinterpret_cast<int4*>(&wt_s[(n << 7) + ((cp ^ (n & 7)) << 3)]) = v;
    }
    __syncthreads();

    f32x16 acc7[2];
    #pragma unroll
    for (int tm = 0; tm < 2; ++tm)
      #pragma unroll
      for (int r = 0; r < 16; ++r) acc7[tm][r] = 0.0f;

    if ((wid & 1) == 0) {                     // waves 0,2 compute the 32-col tile
      #pragma unroll
      for (int kk = 0; kk < 8; ++kk) {
        const int kc = (kk << 1) + lk;
        bf16x8 a0 = *(const bf16x8*)&act_s[(rA0 << 7) + ((kc ^ (rA0 & 7)) << 3)];
        bf16x8 a1 = *(const bf16x8*)&act_s[(rA1 << 7) + ((kc ^ (rA1 & 7)) << 3)];
        bf16x8 b0 = *(const bf16x8*)&wt_s[(lm << 7) + ((kc ^ (lm & 7)) << 3)];
        acc7[0] = __builtin_amdgcn_mfma_f32_32x32x16_bf16(a0, b0, acc7[0], 0, 0, 0);
        acc7[1] = __builtin_amdgcn_mfma_f32_32x32x16_bf16(a1, b0, acc7[1], 0, 0, 0);
      }
    }
    __syncthreads();                          // wt_s reads done; reuse as fp32 scratch

    float* ots = (float*)wt_s;                // [128][9] packed fp32
    if ((wid & 1) == 0 && lm < 9) {
      const int col = lm;
      const float bcol = wsf[768 + col];
      #pragma unroll
      for (int tm = 0; tm < 2; ++tm) {
        const int rbase = m0 + (tm << 5) + (lk << 2);
        #pragma unroll
        for (int r = 0; r < 16; ++r) {
          const int row = rbase + (r & 3) + ((r >> 2) << 3);
          ots[row * 9 + col] = acc7[tm][r] + bcol;
        }
      }
    }
    __syncthreads();

    if (tid < 128) {                          // symmetrize in place (own row)
      const int row = tid;
      float z[9];
      #pragma unroll
      for (int i = 0; i < 9; ++i) z[i] = ots[row * 9 + i];
      #pragma unroll
      for (int rr = 0; rr < 3; ++rr)
        #pragma unroll
        for (int cc = 0; cc < 3; ++cc)
          ots[row * 9 + rr*3 + cc] = 0.5f * (z[rr*3+cc] + z[cc*3+rr]);
    }
    __syncthreads();

    float4* dst = (float4*)(out + (size_t)pbase * 9);   // 4608 B, 16B-aligned
    const float4* srcv = (const float4*)ots;
    for (int s = tid; s < 288; s += 256) dst[s] = srcv[s];
  }
}

extern "C" void kernel_launch(void* const* d_in, const int* in_sizes, int n_in,
                              void* d_out, int out_size, void* d_ws, size_t ws_size,
                              hipStream_t stream) {
  const float* F   = (const float*)d_in[0];
  const float* C   = (const float*)d_in[1];
  const int*   trj = (const int*)d_in[2];
  const float* lat = (const float*)d_in[3];
  const float* W1  = (const float*)d_in[4];
  const float* b1  = (const float*)d_in[5];
  const float* W2  = (const float*)d_in[6];
  const float* b2  = (const float*)d_in[7];
  const float* W3  = (const float*)d_in[8];
  const float* b3  = (const float*)d_in[9];
  const float* W4  = (const float*)d_in[10];
  const float* b4  = (const float*)d_in[11];
  const float* W5  = (const float*)d_in[12];
  const float* b5  = (const float*)d_in[13];
  const float* W6  = (const float*)d_in[14];
  const float* b6  = (const float*)d_in[15];
  const float* W7  = (const float*)d_in[16];
  const float* b7  = (const float*)d_in[17];

  unsigned short* wsb = (unsigned short*)d_ws;           // bf16 Wt, WB_N elems
  float* wsf = (float*)((char*)d_ws + WB_N * 2);         // fp32 biases (16B-aligned)

  prep_weights<<<dim3((PREP_N + 255) / 256), dim3(256), 0, stream>>>(
      W1, W2, W3, W4, W5, W6, W7, b1, b2, b3, b4, b5, b6, b7, wsb, wsf);
  stress_mlp<<<dim3(NBLK), dim3(256), 0, stream>>>(
      F, C, trj, lat, wsb, wsf, (float*)d_out);
}

// Round 3
// 296.777 us; speedup vs baseline: 1.2780x; 1.2780x over previous
//
#include <hip/hip_runtime.h>
#include <hip/hip_bf16.h>
#include <math.h>

// Problem constants
#define BPART   524288
#define NBLK    (BPART / 128)  // 4096
#define W7_OFF  98304          // 6 * 16384 bf16
#define WB_N    102400         // + 32*128 (padded W7t), bf16 count
#define BIAS_N  800            // 6*128 + 32 floats
#define PREP_N  (WB_N + BIAS_N)

typedef __bf16 bf16x8 __attribute__((ext_vector_type(8)));
typedef float  f32x16 __attribute__((ext_vector_type(16)));
typedef float  f32x4  __attribute__((ext_vector_type(4)));

#define MFMA __builtin_amdgcn_mfma_f32_32x32x16_bf16

__device__ __forceinline__ unsigned short f2bf(float f) {
  union { float f; unsigned u; } v; v.f = f;
  unsigned r = v.u + 0x7fffu + ((v.u >> 16) & 1u);   // RNE
  return (unsigned short)(r >> 16);
}
// pack two fp32 -> bf16x2 (round-half-up: tie-only deviation from RNE)
__device__ __forceinline__ unsigned pack_bf16(float a, float b) {
  unsigned ua = __builtin_bit_cast(unsigned, a) + 0x8000u;
  unsigned ub = __builtin_bit_cast(unsigned, b) + 0x8000u;
  return __builtin_amdgcn_perm(ub, ua, 0x07060302u);  // [ua_hi16 | ub_hi16]
}
// XOR-swizzled LDS index (16B chunk swizzle; row stride 128 bf16 = 256B)
__device__ __forceinline__ int swz(int row, int col) {
  return (row << 7) | ((((col >> 3) ^ (row & 7)) << 3) | (col & 7));
}
// tanh-form GELU, minimal: z * sigmoid(2y), log2e folded into coeffs.
// 5 full-rate + exp2 + rcp. Saturates correctly for |z| large.
__device__ __forceinline__ float gelu_t(float z) {
  float z2 = z * z;
  float t  = fmaf(0.1029432f, z2, 2.30220818f);
  float yp = z * t;
  float e  = __builtin_amdgcn_exp2f(-yp);
  float r  = __builtin_amdgcn_rcpf(e + 1.0f);
  return z * r;
}
// async 16B global->LDS (lane-linear dest, per guide m97/m104)
__device__ __forceinline__ void cp16(const void* g, void* l) {
  __builtin_amdgcn_global_load_lds(
      (const __attribute__((address_space(1))) void*)g,
      (__attribute__((address_space(3))) void*)l, 16, 0, 0);
}

// ---- prep: cast+transpose fp32 weights into d_ws as the EXACT swizzled
// LDS image (so main-kernel staging is lane-linear global_load_lds) ----
__global__ void prep_weights(
    const float* __restrict__ W1, const float* __restrict__ W2,
    const float* __restrict__ W3, const float* __restrict__ W4,
    const float* __restrict__ W5, const float* __restrict__ W6,
    const float* __restrict__ W7,
    const float* __restrict__ b1, const float* __restrict__ b2,
    const float* __restrict__ b3, const float* __restrict__ b4,
    const float* __restrict__ b5, const float* __restrict__ b6,
    const float* __restrict__ b7,
    unsigned short* __restrict__ wsb, float* __restrict__ wsf)
{
  int idx = blockIdx.x * 256 + threadIdx.x;
  if (idx < WB_N) {
    unsigned short v = 0;
    if (idx < W7_OFF) {                     // W1..W6: Wt[n][k] swizzled
      int l = idx >> 14;
      int o = idx & 16383;
      int n = o >> 7, e = o & 127;
      int k = (((e >> 3) ^ (n & 7)) << 3) | (e & 7);
      const float* W = (l==0)?W1:(l==1)?W2:(l==2)?W3:(l==3)?W4:(l==4)?W5:W6;
      float x = (l == 0) ? ((k < 89) ? W[k*128 + n] : 0.0f)   // K-pad 89->128
                         : W[k*128 + n];
      v = f2bf(x);
    } else {                                // W7t padded to 32 rows, swizzled
      int o = idx - W7_OFF;
      int n = o >> 7, e = o & 127;
      int k = (((e >> 3) ^ (n & 7)) << 3) | (e & 7);
      v = (n < 9) ? f2bf(W7[k*9 + n]) : (unsigned short)0;
    }
    wsb[idx] = v;
  } else if (idx < PREP_N) {                // biases, fp32
    int r = idx - WB_N;
    float x;
    if (r < 768) {
      int l = r >> 7, n = r & 127;
      const float* bb = (l==0)?b1:(l==1)?b2:(l==2)?b3:(l==3)?b4:(l==4)?b5:b6;
      x = bb[n];
    } else {
      int n = r - 768;
      x = (n < 9) ? b7[n] : 0.0f;
    }
    wsf[r] = x;
  }
}

// ---- main fused kernel: features + 7-layer MLP + symmetrize ----
__global__ __launch_bounds__(256, 2) void stress_mlp(
    const float* __restrict__ F, const float* __restrict__ Cmat,
    const int* __restrict__ traj, const float* __restrict__ latent,
    const unsigned short* __restrict__ wst, const float* __restrict__ wsf,
    float* __restrict__ out)
{
  __shared__ __align__(16) unsigned short act_s[128 * 128];  // 32 KB
  __shared__ __align__(16) unsigned short wt_s[128 * 128];   // 32 KB

  const int tid  = threadIdx.x;
  const int lane = tid & 63;
  const int wid  = tid >> 6;
  const int lm   = lane & 31;
  const int lk   = lane >> 5;              // k-half
  const int m0   = (wid >> 1) << 6;        // wave particle-row origin (0/64)
  const int n0   = (wid & 1) << 6;         // wave out-feature origin (0/64)
  const int pbase = (int)blockIdx.x << 7;

  // issue W1 staging immediately (async DMA, overlaps feature phase)
  {
    const char* src = (const char*)wst;
    char* dst = (char*)wt_s;
    #pragma unroll
    for (int i = 0; i < 8; ++i)
      cp16(src + i*4096 + tid*16, dst + i*4096 + tid*16);
  }

  // ---------- phase 0: build input activations (89 feats, zero-pad to 128) ----------
  if (tid < 128) {
    const int row = tid;
    const int p   = pbase + row;
    float f[9];
    #pragma unroll
    for (int i = 0; i < 9; ++i) f[i] = F[p * 9 + i];
    float fft[9];
    #pragma unroll
    for (int i = 0; i < 3; ++i)
      #pragma unroll
      for (int k = 0; k < 3; ++k)
        fft[i*3+k] = f[i*3]*f[k*3] + f[i*3+1]*f[k*3+1] + f[i*3+2]*f[k*3+2];
    float det = f[0]*(f[4]*f[8]-f[5]*f[7]) - f[1]*(f[3]*f[8]-f[5]*f[6])
              + f[2]*(f[3]*f[7]-f[4]*f[6]);
    float J  = fmaxf(det, 1e-6f);
    float J1 = fmaxf(f[0], 1e-6f);
    // singular values = sqrt(eig(F F^T)); analytic symmetric 3x3 eigensolve (fp64)
    double a00=fft[0], a01=fft[1], a02=fft[2], a11=fft[4], a12=fft[5], a22=fft[8];
    double q  = (a00+a11+a22) * (1.0/3.0);
    double d0 = a00-q, d1 = a11-q, d2 = a22-q;
    double p2 = d0*d0 + d1*d1 + d2*d2 + 2.0*(a01*a01 + a02*a02 + a12*a12);
    double e0, e1, e2;
    if (p2 < 1e-26) { e0 = e1 = e2 = q; }
    else {
      double pp = sqrt(p2 * (1.0/6.0));
      double inv = 1.0 / pp;
      double b00=d0*inv, b11=d1*inv, b22=d2*inv, b01=a01*inv, b02=a02*inv, b12=a12*inv;
      double detb = b00*(b11*b22-b12*b12) - b01*(b01*b22-b12*b02) + b02*(b01*b12-b11*b02);
      double rr = 0.5 * detb;
      rr = rr > 1.0 ? 1.0 : (rr < -1.0 ? -1.0 : rr);
      double phi = acos(rr) * (1.0/3.0);
      e0 = q + 2.0*pp*cos(phi);
      e2 = q + 2.0*pp*cos(phi + 2.0943951023931953);  // +2pi/3
      e1 = 3.0*q - e0 - e2;
    }
    float s0 = sqrtf(fmaxf((float)e0, 0.f));
    float s1 = sqrtf(fmaxf((float)e1, 0.f));
    float s2 = sqrtf(fmaxf((float)e2, 0.f));
    #pragma unroll
    for (int i = 0; i < 9; ++i) act_s[swz(row, i)] = f2bf(fft[i]);
    act_s[swz(row,  9)] = f2bf(logf(J));
    act_s[swz(row, 10)] = f2bf(s0);
    act_s[swz(row, 11)] = f2bf(s1);
    act_s[swz(row, 12)] = f2bf(s2);
    act_s[swz(row, 13)] = f2bf(J);
    act_s[swz(row, 14)] = f2bf(logf(J1));
    act_s[swz(row, 15)] = f2bf(J1);
    #pragma unroll
    for (int i = 0; i < 9; ++i) act_s[swz(row, 16 + i)] = f2bf(Cmat[p*9 + i]);
  } else {
    const int row = tid - 128;
    const int t = traj[0];
    const float* lat = latent + t * 64;
    for (int j = 0; j < 64; ++j) act_s[swz(row, 25 + j)] = f2bf(lat[j]);
    for (int j = 89; j < 128; ++j) act_s[swz(row, j)] = 0;
  }

  // fragment source rows
  const int mr0 = m0 + lm,      mr1 = m0 + 32 + lm;   // X rows (particles)
  const int nr0 = n0 + lm,      nr1 = n0 + 32 + lm;   // Wt rows (out features)

  f32x16 acc[2][2];   // acc[tn][tm]: D[n][m], lane holds particle m, regs n

  // ---------- layers 1..6 (128x128, gelu) ----------
  for (int l = 0; l < 6; ++l) {
    // bias quads -> accumulator init (n is reg-indexed; 8 loads shared by both tm)
    const float* bl = wsf + (l << 7);
    #pragma unroll
    for (int tn = 0; tn < 2; ++tn) {
      #pragma unroll
      for (int q = 0; q < 4; ++q) {
        f32x4 bq = *(const f32x4*)(bl + n0 + (tn << 5) + (q << 3) + (lk << 2));
        #pragma unroll
        for (int j = 0; j < 4; ++j) {
          acc[tn][0][4*q + j] = bq[j];
          acc[tn][1][4*q + j] = bq[j];
        }
      }
    }

    __syncthreads();   // W(l) staged (vmcnt drained) + act(l) writes visible

    #pragma unroll
    for (int kk = 0; kk < 8; ++kk) {
      const int kc = (kk << 1) + lk;
      bf16x8 x0 = *(const bf16x8*)&act_s[(mr0 << 7) + ((kc ^ (mr0 & 7)) << 3)];
      bf16x8 x1 = *(const bf16x8*)&act_s[(mr1 << 7) + ((kc ^ (mr1 & 7)) << 3)];
      bf16x8 w0 = *(const bf16x8*)&wt_s[(nr0 << 7) + ((kc ^ (nr0 & 7)) << 3)];
      bf16x8 w1 = *(const bf16x8*)&wt_s[(nr1 << 7) + ((kc ^ (nr1 & 7)) << 3)];
      acc[0][0] = MFMA(w0, x0, acc[0][0], 0, 0, 0);
      acc[0][1] = MFMA(w0, x1, acc[0][1], 0, 0, 0);
      acc[1][0] = MFMA(w1, x0, acc[1][0], 0, 0, 0);
      acc[1][1] = MFMA(w1, x1, acc[1][1], 0, 0, 0);
    }
    __syncthreads();   // all act/wt reads done before overwrite

    // stage next-layer weights (async) while epilogue computes
    if (l < 5) {
      const char* src = (const char*)(wst + ((l + 1) << 14));
      char* dst = (char*)wt_s;
      #pragma unroll
      for (int i = 0; i < 8; ++i)
        cp16(src + i*4096 + tid*16, dst + i*4096 + tid*16);
    } else {
      const char* src = (const char*)(wst + W7_OFF);
      char* dst = (char*)wt_s;
      #pragma unroll
      for (int i = 0; i < 2; ++i)
        cp16(src + i*4096 + tid*16, dst + i*4096 + tid*16);
    }

    // epilogue: gelu + pack pairs + b64 swizzled stores (row-contiguous quads)
    #pragma unroll
    for (int tm = 0; tm < 2; ++tm) {
      const int m    = m0 + (tm << 5) + lm;
      const int rowb = m << 7;
      const int rx   = m & 7;
      #pragma unroll
      for (int tn = 0; tn < 2; ++tn) {
        const int cb = ((n0 + (tn << 5)) >> 3);   // chunk base
        #pragma unroll
        for (int q = 0; q < 4; ++q) {
          float g0 = gelu_t(acc[tn][tm][4*q + 0]);
          float g1 = gelu_t(acc[tn][tm][4*q + 1]);
          float g2 = gelu_t(acc[tn][tm][4*q + 2]);
          float g3 = gelu_t(acc[tn][tm][4*q + 3]);
          uint2 u;
          u.x = pack_bf16(g0, g1);
          u.y = pack_bf16(g2, g3);
          const int off = rowb + (((cb + q) ^ rx) << 3) + (lk << 2);
          *reinterpret_cast<uint2*>(&act_s[off]) = u;
        }
      }
    }
  }

  // ---------- layer 7 (128 -> 9, no activation) + symmetrize, fp32 path ----------
  {
    f32x16 acc7[2];
    if ((wid & 1) == 0) {               // n0==0 waves own cols 0..31 (only 0..8 real)
      f32x4 bq0 = *(const f32x4*)(wsf + 768 + (lk << 2));       // n = 4lk+j
      f32x4 bq1 = *(const f32x4*)(wsf + 768 + 8 + (lk << 2));   // n = 8+4lk+j
      #pragma unroll
      for (int tm = 0; tm < 2; ++tm) {
        #pragma unroll
        for (int j = 0; j < 4; ++j) {
          acc7[tm][j]     = bq0[j];
          acc7[tm][4 + j] = bq1[j];
        }
        #pragma unroll
        for (int r = 8; r < 16; ++r) acc7[tm][r] = 0.0f;
      }
    }
    __syncthreads();                    // W7 staged + act(7) writes visible

    if ((wid & 1) == 0) {
      #pragma unroll
      for (int kk = 0; kk < 8; ++kk) {
        const int kc = (kk << 1) + lk;
        bf16x8 x0 = *(const bf16x8*)&act_s[(mr0 << 7) + ((kc ^ (mr0 & 7)) << 3)];
        bf16x8 x1 = *(const bf16x8*)&act_s[(mr1 << 7) + ((kc ^ (mr1 & 7)) << 3)];
        bf16x8 w0 = *(const bf16x8*)&wt_s[(lm << 7) + ((kc ^ (lm & 7)) << 3)];
        acc7[0] = MFMA(w0, x0, acc7[0], 0, 0, 0);
        acc7[1] = MFMA(w0, x1, acc7[1], 0, 0, 0);
      }
    }
    __syncthreads();                    // wt_s reads done; reuse as fp32 scratch

    float* ots = (float*)wt_s;          // [128][9] packed fp32
    if ((wid & 1) == 0) {
      #pragma unroll
      for (int tm = 0; tm < 2; ++tm) {
        const int m = m0 + (tm << 5) + lm;
        #pragma unroll
        for (int j = 0; j < 4; ++j)
          ots[m * 9 + (lk << 2) + j] = acc7[tm][j];   // n = 4lk+j
        if (lk == 0) ots[m * 9 + 8] = acc7[tm][4];    // n = 8
      }
    }
    __syncthreads();

    if (tid < 128) {                    // symmetrize in place (own row)
      const int row = tid;
      float z[9];
      #pragma unroll
      for (int i = 0; i < 9; ++i) z[i] = ots[row * 9 + i];
      #pragma unroll
      for (int rr = 0; rr < 3; ++rr)
        #pragma unroll
        for (int cc = 0; cc < 3; ++cc)
          ots[row * 9 + rr*3 + cc] = 0.5f * (z[rr*3+cc] + z[cc*3+rr]);
    }
    __syncthreads();

    float4* dst = (float4*)(out + (size_t)pbase * 9);   // 4608 B, 16B-aligned
    const float4* srcv = (const float4*)ots;
    for (int s = tid; s < 288; s += 256) dst[s] = srcv[s];
  }
}

extern "C" void kernel_launch(void* const* d_in, const int* in_sizes, int n_in,
                              void* d_out, int out_size, void* d_ws, size_t ws_size,
                              hipStream_t stream) {
  const float* F   = (const float*)d_in[0];
  const float* C   = (const float*)d_in[1];
  const int*   trj = (const int*)d_in[2];
  const float* lat = (const float*)d_in[3];
  const float* W1  = (const float*)d_in[4];
  const float* b1  = (const float*)d_in[5];
  const float* W2  = (const float*)d_in[6];
  const float* b2  = (const float*)d_in[7];
  const float* W3  = (const float*)d_in[8];
  const float* b3  = (const float*)d_in[9];
  const float* W4  = (const float*)d_in[10];
  const float* b4  = (const float*)d_in[11];
  const float* W5  = (const float*)d_in[12];
  const float* b5  = (const float*)d_in[13];
  const float* W6  = (const float*)d_in[14];
  const float* b6  = (const float*)d_in[15];
  const float* W7  = (const float*)d_in[16];
  const float* b7  = (const float*)d_in[17];

  unsigned short* wsb = (unsigned short*)d_ws;           // bf16 swizzled Wt image
  float* wsf = (float*)((char*)d_ws + WB_N * 2);         // fp32 biases (16B-aligned)

  prep_weights<<<dim3((PREP_N + 255) / 256), dim3(256), 0, stream>>>(
      W1, W2, W3, W4, W5, W6, W7, b1, b2, b3, b4, b5, b6, b7, wsb, wsf);
  stress_mlp<<<dim3(NBLK), dim3(256), 0, stream>>>(
      F, C, trj, lat, wsb, wsf, (float*)d_out);
}

// Round 4
// 287.939 us; speedup vs baseline: 1.3172x; 1.0307x over previous
//
#include <hip/hip_runtime.h>
#include <hip/hip_bf16.h>
#include <math.h>

// Problem constants
#define BPART   524288
#define NBLK    (BPART / 128)  // 4096
#define W7_OFF  98304          // 6 * 16384 bf16
#define WB_N    102400         // + 32*128 (padded W7t), bf16 count
#define BIAS_N  800            // 6*128 + 32 floats
#define PREP_N  (WB_N + BIAS_N)

typedef __bf16 bf16x8 __attribute__((ext_vector_type(8)));
typedef float  f32x16 __attribute__((ext_vector_type(16)));
typedef float  f32x4  __attribute__((ext_vector_type(4)));
typedef float  f32x2  __attribute__((ext_vector_type(2)));

#define MFMA __builtin_amdgcn_mfma_f32_32x32x16_bf16

__device__ __forceinline__ unsigned short f2bf(float f) {
  union { float f; unsigned u; } v; v.f = f;
  unsigned r = v.u + 0x7fffu + ((v.u >> 16) & 1u);   // RNE
  return (unsigned short)(r >> 16);
}
// pack two fp32 -> bf16x2 (verified in round 3: low16 = a, high16 = b)
__device__ __forceinline__ unsigned pack_bf16(float a, float b) {
  unsigned ua = __builtin_bit_cast(unsigned, a) + 0x8000u;
  unsigned ub = __builtin_bit_cast(unsigned, b) + 0x8000u;
  return __builtin_amdgcn_perm(ub, ua, 0x07060302u);
}
// XOR-swizzled LDS index (16B chunk swizzle; row stride 128 bf16 = 256B)
__device__ __forceinline__ int swz(int row, int col) {
  return (row << 7) | ((((col >> 3) ^ (row & 7)) << 3) | (col & 7));
}

// packed fp32 VALU (VOP3P, gfx90a+)
__device__ __forceinline__ f32x2 pk_mul(f32x2 a, f32x2 b) {
  f32x2 d; asm("v_pk_mul_f32 %0, %1, %2" : "=v"(d) : "v"(a), "v"(b)); return d;
}
__device__ __forceinline__ f32x2 pk_fma(f32x2 a, f32x2 b, f32x2 c) {
  f32x2 d; asm("v_pk_fma_f32 %0, %1, %2, %3" : "=v"(d) : "v"(a), "v"(b), "v"(c)); return d;
}
// tanh-form GELU on a pair; poly part packed, transcendentals scalar
__device__ __forceinline__ f32x2 gelu2(f32x2 z) {
  const f32x2 c1 = {0.1029432f, 0.1029432f};
  const f32x2 c0 = {2.30220818f, 2.30220818f};
  f32x2 z2 = pk_mul(z, z);
  f32x2 t  = pk_fma(z2, c1, c0);
  f32x2 yp = pk_mul(z, t);
  float e0 = __builtin_amdgcn_exp2f(-yp.x);
  float e1 = __builtin_amdgcn_exp2f(-yp.y);
  float r0 = __builtin_amdgcn_rcpf(e0 + 1.0f);
  float r1 = __builtin_amdgcn_rcpf(e1 + 1.0f);
  f32x2 g; g.x = z.x * r0; g.y = z.y * r1;
  return g;
}
// async 16B global->LDS (lane-linear dest)
__device__ __forceinline__ void cp16(const void* g, void* l) {
  __builtin_amdgcn_global_load_lds(
      (const __attribute__((address_space(1))) void*)g,
      (__attribute__((address_space(3))) void*)l, 16, 0, 0);
}

// ---- prep: cast+transpose fp32 weights into d_ws as the EXACT swizzled
// LDS image (so main-kernel staging is lane-linear global_load_lds) ----
__global__ void prep_weights(
    const float* __restrict__ W1, const float* __restrict__ W2,
    const float* __restrict__ W3, const float* __restrict__ W4,
    const float* __restrict__ W5, const float* __restrict__ W6,
    const float* __restrict__ W7,
    const float* __restrict__ b1, const float* __restrict__ b2,
    const float* __restrict__ b3, const float* __restrict__ b4,
    const float* __restrict__ b5, const float* __restrict__ b6,
    const float* __restrict__ b7,
    unsigned short* __restrict__ wsb, float* __restrict__ wsf)
{
  int idx = blockIdx.x * 256 + threadIdx.x;
  if (idx < WB_N) {
    unsigned short v = 0;
    if (idx < W7_OFF) {                     // W1..W6: Wt[n][k] swizzled
      int l = idx >> 14;
      int o = idx & 16383;
      int n = o >> 7, e = o & 127;
      int k = (((e >> 3) ^ (n & 7)) << 3) | (e & 7);
      const float* W = (l==0)?W1:(l==1)?W2:(l==2)?W3:(l==3)?W4:(l==4)?W5:W6;
      float x = (l == 0) ? ((k < 89) ? W[k*128 + n] : 0.0f)   // K-pad 89->128
                         : W[k*128 + n];
      v = f2bf(x);
    } else {                                // W7t padded to 32 rows, swizzled
      int o = idx - W7_OFF;
      int n = o >> 7, e = o & 127;
      int k = (((e >> 3) ^ (n & 7)) << 3) | (e & 7);
      v = (n < 9) ? f2bf(W7[k*9 + n]) : (unsigned short)0;
    }
    wsb[idx] = v;
  } else if (idx < PREP_N) {                // biases, fp32
    int r = idx - WB_N;
    float x;
    if (r < 768) {
      int l = r >> 7, n = r & 127;
      const float* bb = (l==0)?b1:(l==1)?b2:(l==2)?b3:(l==3)?b4:(l==4)?b5:b6;
      x = bb[n];
    } else {
      int n = r - 768;
      x = (n < 9) ? b7[n] : 0.0f;
    }
    wsf[r] = x;
  }
}

// ---- main fused kernel: features + 7-layer MLP + symmetrize ----
__global__ __launch_bounds__(256, 2) void stress_mlp(
    const float* __restrict__ F, const float* __restrict__ Cmat,
    const int* __restrict__ traj, const float* __restrict__ latent,
    const unsigned short* __restrict__ wst, const float* __restrict__ wsf,
    float* __restrict__ out)
{
  __shared__ __align__(16) unsigned short act_s[128 * 128];  // 32 KB
  __shared__ __align__(16) unsigned short wt_s[128 * 128];   // 32 KB

  const int tid  = threadIdx.x;
  const int lane = tid & 63;
  const int wid  = tid >> 6;
  const int lm   = lane & 31;
  const int lk   = lane >> 5;              // k-half
  const int m0   = (wid >> 1) << 6;        // wave particle-row origin (0/64)
  const int n0   = (wid & 1) << 6;         // wave out-feature origin (0/64)
  const int pbase = (int)blockIdx.x << 7;

  // issue W1 staging immediately (async DMA, overlaps feature phase)
  {
    const char* src = (const char*)wst;
    char* dst = (char*)wt_s;
    #pragma unroll
    for (int i = 0; i < 8; ++i)
      cp16(src + i*4096 + tid*16, dst + i*4096 + tid*16);
  }

  // ---------- phase 0: build input activations (89 feats, zero-pad to 128) ----------
  if (tid < 128) {
    const int row = tid;
    const int p   = pbase + row;
    float f[9];
    #pragma unroll
    for (int i = 0; i < 9; ++i) f[i] = F[p * 9 + i];
    float fft[9];
    #pragma unroll
    for (int i = 0; i < 3; ++i)
      #pragma unroll
      for (int k = 0; k < 3; ++k)
        fft[i*3+k] = f[i*3]*f[k*3] + f[i*3+1]*f[k*3+1] + f[i*3+2]*f[k*3+2];
    float det = f[0]*(f[4]*f[8]-f[5]*f[7]) - f[1]*(f[3]*f[8]-f[5]*f[6])
              + f[2]*(f[3]*f[7]-f[4]*f[6]);
    float J  = fmaxf(det, 1e-6f);
    float J1 = fmaxf(f[0], 1e-6f);
    // singular values = sqrt(eig(F F^T)); analytic symmetric 3x3 eigensolve, fp32.
    // fp32 abs eigenvalue err ~1e-5 << bf16 feature rounding (0.4% rel).
    float a00=fft[0], a01=fft[1], a02=fft[2], a11=fft[4], a12=fft[5], a22=fft[8];
    float q  = (a00+a11+a22) * (1.0f/3.0f);
    float d0 = a00-q, d1 = a11-q, d2 = a22-q;
    float p2 = d0*d0 + d1*d1 + d2*d2 + 2.0f*(a01*a01 + a02*a02 + a12*a12);
    float e0, e1, e2;
    if (p2 < 1e-14f) { e0 = e1 = e2 = q; }
    else {
      float pp  = sqrtf(p2 * (1.0f/6.0f));
      float inv = 1.0f / pp;
      float b00=d0*inv, b11=d1*inv, b22=d2*inv, b01=a01*inv, b02=a02*inv, b12=a12*inv;
      float detb = b00*(b11*b22-b12*b12) - b01*(b01*b22-b12*b02) + b02*(b01*b12-b11*b02);
      float rr = 0.5f * detb;
      rr = fminf(fmaxf(rr, -1.0f), 1.0f);
      // phi in revolutions; v_cos takes revolutions, args in [0, 1/2]
      float pr = acosf(rr) * (1.0f / (3.0f * 6.2831853071795864f));
      e0 = q + 2.0f*pp*__builtin_amdgcn_cosf(pr);
      e2 = q + 2.0f*pp*__builtin_amdgcn_cosf(pr + (1.0f/3.0f));
      e1 = 3.0f*q - e0 - e2;
    }
    float s0 = sqrtf(fmaxf(e0, 0.f));
    float s1 = sqrtf(fmaxf(e1, 0.f));
    float s2 = sqrtf(fmaxf(e2, 0.f));
    #pragma unroll
    for (int i = 0; i < 9; ++i) act_s[swz(row, i)] = f2bf(fft[i]);
    act_s[swz(row,  9)] = f2bf(logf(J));
    act_s[swz(row, 10)] = f2bf(s0);
    act_s[swz(row, 11)] = f2bf(s1);
    act_s[swz(row, 12)] = f2bf(s2);
    act_s[swz(row, 13)] = f2bf(J);
    act_s[swz(row, 14)] = f2bf(logf(J1));
    act_s[swz(row, 15)] = f2bf(J1);
    #pragma unroll
    for (int i = 0; i < 9; ++i) act_s[swz(row, 16 + i)] = f2bf(Cmat[p*9 + i]);
  } else {
    const int row = tid - 128;
    const int t = traj[0];
    const float* lat = latent + t * 64;
    for (int j = 0; j < 64; ++j) act_s[swz(row, 25 + j)] = f2bf(lat[j]);
    for (int j = 89; j < 128; ++j) act_s[swz(row, j)] = 0;
  }

  // fragment source rows
  const int mr0 = m0 + lm,      mr1 = m0 + 32 + lm;   // X rows (particles)
  const int nr0 = n0 + lm,      nr1 = n0 + 32 + lm;   // Wt rows (out features)

  f32x16 acc[2][2];   // acc[tn][tm]: D[n][m], lane holds particle m, regs n
  union BF { f32x16 v; f32x4 q[4]; };

  // ---------- layers 1..6 (128x128, gelu) ----------
  for (int l = 0; l < 6; ++l) {
    // bias fragment: 4 contiguous 16B loads = the f32x16 C operand, zero movs.
    // acc[tn][*][4q+j] must equal b[n0+tn*32+8q+4lk+j]  (C/D layout n-mapping)
    BF bias[2];
    const float* bl = wsf + (l << 7);
    #pragma unroll
    for (int tn = 0; tn < 2; ++tn)
      #pragma unroll
      for (int qq = 0; qq < 4; ++qq)
        bias[tn].q[qq] = *(const f32x4*)(bl + n0 + (tn << 5) + (qq << 3) + (lk << 2));

    __syncthreads();   // W(l) staged (vmcnt drained) + act(l) writes visible

    // kk = 0: bias rides in as the MFMA C operand
    {
      bf16x8 x0 = *(const bf16x8*)&act_s[(mr0 << 7) + ((lk ^ (mr0 & 7)) << 3)];
      bf16x8 x1 = *(const bf16x8*)&act_s[(mr1 << 7) + ((lk ^ (mr1 & 7)) << 3)];
      bf16x8 w0 = *(const bf16x8*)&wt_s[(nr0 << 7) + ((lk ^ (nr0 & 7)) << 3)];
      bf16x8 w1 = *(const bf16x8*)&wt_s[(nr1 << 7) + ((lk ^ (nr1 & 7)) << 3)];
      acc[0][0] = MFMA(w0, x0, bias[0].v, 0, 0, 0);
      acc[0][1] = MFMA(w0, x1, bias[0].v, 0, 0, 0);
      acc[1][0] = MFMA(w1, x0, bias[1].v, 0, 0, 0);
      acc[1][1] = MFMA(w1, x1, bias[1].v, 0, 0, 0);
    }
    #pragma unroll
    for (int kk = 1; kk < 8; ++kk) {
      const int kc = (kk << 1) + lk;
      bf16x8 x0 = *(const bf16x8*)&act_s[(mr0 << 7) + ((kc ^ (mr0 & 7)) << 3)];
      bf16x8 x1 = *(const bf16x8*)&act_s[(mr1 << 7) + ((kc ^ (mr1 & 7)) << 3)];
      bf16x8 w0 = *(const bf16x8*)&wt_s[(nr0 << 7) + ((kc ^ (nr0 & 7)) << 3)];
      bf16x8 w1 = *(const bf16x8*)&wt_s[(nr1 << 7) + ((kc ^ (nr1 & 7)) << 3)];
      acc[0][0] = MFMA(w0, x0, acc[0][0], 0, 0, 0);
      acc[0][1] = MFMA(w0, x1, acc[0][1], 0, 0, 0);
      acc[1][0] = MFMA(w1, x0, acc[1][0], 0, 0, 0);
      acc[1][1] = MFMA(w1, x1, acc[1][1], 0, 0, 0);
    }
    __syncthreads();   // all act/wt reads done before overwrite

    // stage next-layer weights (async) while epilogue computes
    if (l < 5) {
      const char* src = (const char*)(wst + ((l + 1) << 14));
      char* dst = (char*)wt_s;
      #pragma unroll
      for (int i = 0; i < 8; ++i)
        cp16(src + i*4096 + tid*16, dst + i*4096 + tid*16);
    } else {
      const char* src = (const char*)(wst + W7_OFF);
      char* dst = (char*)wt_s;
      #pragma unroll
      for (int i = 0; i < 2; ++i)
        cp16(src + i*4096 + tid*16, dst + i*4096 + tid*16);
    }

    // epilogue: gelu (pk-f32 poly) + pack pairs + b64 swizzled stores
    #pragma unroll
    for (int tm = 0; tm < 2; ++tm) {
      const int m    = m0 + (tm << 5) + lm;
      const int rowb = m << 7;
      const int rx   = m & 7;
      #pragma unroll
      for (int tn = 0; tn < 2; ++tn) {
        const int cb = ((n0 + (tn << 5)) >> 3);   // chunk base
        #pragma unroll
        for (int q = 0; q < 4; ++q) {
          f32x2 za; za.x = acc[tn][tm][4*q + 0]; za.y = acc[tn][tm][4*q + 1];
          f32x2 zb; zb.x = acc[tn][tm][4*q + 2]; zb.y = acc[tn][tm][4*q + 3];
          f32x2 ga = gelu2(za);
          f32x2 gb = gelu2(zb);
          uint2 u;
          u.x = pack_bf16(ga.x, ga.y);
          u.y = pack_bf16(gb.x, gb.y);
          const int off = rowb + (((cb + q) ^ rx) << 3) + (lk << 2);
          *reinterpret_cast<uint2*>(&act_s[off]) = u;
        }
      }
    }
  }

  // ---------- layer 7 (128 -> 9, no activation) + symmetrize, fp32 path ----------
  {
    BF bias7;
    #pragma unroll
    for (int qq = 0; qq < 4; ++qq)
      bias7.q[qq] = *(const f32x4*)(wsf + 768 + (qq << 3) + (lk << 2));

    __syncthreads();                    // W7 staged + act(7) writes visible

    f32x16 acc7[2];
    if ((wid & 1) == 0) {               // n0==0 waves own cols 0..31 (0..8 real)
      {
        bf16x8 x0 = *(const bf16x8*)&act_s[(mr0 << 7) + ((lk ^ (mr0 & 7)) << 3)];
        bf16x8 x1 = *(const bf16x8*)&act_s[(mr1 << 7) + ((lk ^ (mr1 & 7)) << 3)];
        bf16x8 w0 = *(const bf16x8*)&wt_s[(lm << 7) + ((lk ^ (lm & 7)) << 3)];
        acc7[0] = MFMA(w0, x0, bias7.v, 0, 0, 0);
        acc7[1] = MFMA(w0, x1, bias7.v, 0, 0, 0);
      }
      #pragma unroll
      for (int kk = 1; kk < 8; ++kk) {
        const int kc = (kk << 1) + lk;
        bf16x8 x0 = *(const bf16x8*)&act_s[(mr0 << 7) + ((kc ^ (mr0 & 7)) << 3)];
        bf16x8 x1 = *(const bf16x8*)&act_s[(mr1 << 7) + ((kc ^ (mr1 & 7)) << 3)];
        bf16x8 w0 = *(const bf16x8*)&wt_s[(lm << 7) + ((kc ^ (lm & 7)) << 3)];
        acc7[0] = MFMA(w0, x0, acc7[0], 0, 0, 0);
        acc7[1] = MFMA(w0, x1, acc7[1], 0, 0, 0);
      }
    }
    __syncthreads();                    // wt_s reads done; reuse as fp32 scratch

    float* ots = (float*)wt_s;          // [128][9] packed fp32
    if ((wid & 1) == 0) {
      #pragma unroll
      for (int tm = 0; tm < 2; ++tm) {
        const int m = m0 + (tm << 5) + lm;
        #pragma unroll
        for (int j = 0; j < 4; ++j)
          ots[m * 9 + (lk << 2) + j] = acc7[tm][j];   // n = 4lk+j
        if (lk == 0) ots[m * 9 + 8] = acc7[tm][4];    // n = 8
      }
    }
    __syncthreads();

    if (tid < 128) {                    // symmetrize in place (own row)
      const int row = tid;
      float z[9];
      #pragma unroll
      for (int i = 0; i < 9; ++i) z[i] = ots[row * 9 + i];
      #pragma unroll
      for (int rr = 0; rr < 3; ++rr)
        #pragma unroll
        for (int cc = 0; cc < 3; ++cc)
          ots[row * 9 + rr*3 + cc] = 0.5f * (z[rr*3+cc] + z[cc*3+rr]);
    }
    __syncthreads();

    float4* dst = (float4*)(out + (size_t)pbase * 9);   // 4608 B, 16B-aligned
    const float4* srcv = (const float4*)ots;
    for (int s = tid; s < 288; s += 256) dst[s] = srcv[s];
  }
}

extern "C" void kernel_launch(void* const* d_in, const int* in_sizes, int n_in,
                              void* d_out, int out_size, void* d_ws, size_t ws_size,
                              hipStream_t stream) {
  const float* F   = (const float*)d_in[0];
  const float* C   = (const float*)d_in[1];
  const int*   trj = (const int*)d_in[2];
  const float* lat = (const float*)d_in[3];
  const float* W1  = (const float*)d_in[4];
  const float* b1  = (const float*)d_in[5];
  const float* W2  = (const float*)d_in[6];
  const float* b2  = (const float*)d_in[7];
  const float* W3  = (const float*)d_in[8];
  const float* b3  = (const float*)d_in[9];
  const float* W4  = (const float*)d_in[10];
  const float* b4  = (const float*)d_in[11];
  const float* W5  = (const float*)d_in[12];
  const float* b5  = (const float*)d_in[13];
  const float* W6  = (const float*)d_in[14];
  const float* b6  = (const float*)d_in[15];
  const float* W7  = (const float*)d_in[16];
  const float* b7  = (const float*)d_in[17];

  unsigned short* wsb = (unsigned short*)d_ws;           // bf16 swizzled Wt image
  float* wsf = (float*)((char*)d_ws + WB_N * 2);         // fp32 biases (16B-aligned)

  prep_weights<<<dim3((PREP_N + 255) / 256), dim3(256), 0, stream>>>(
      W1, W2, W3, W4, W5, W6, W7, b1, b2, b3, b4, b5, b6, b7, wsb, wsf);
  stress_mlp<<<dim3(NBLK), dim3(256), 0, stream>>>(
      F, C, trj, lat, wsb, wsf, (float*)d_out);
}